// Round 8
// baseline (698.169 us; speedup 1.0000x reference)
//
#include <hip/hip_runtime.h>

#define HH 512
#define WW 512
#define NPIX (HH * WW)          // 262144
#define NIMG 16
#define KPTS 1024
#define NWORDS (NPIX / 64)      // 4096 u64 mask words per image

// ---------------------------------------------------------------------------
// Kernel 1: binarize + uniform LBP (P=8,R=1) — PURE BOOLEAN form. (unchanged)
// ---------------------------------------------------------------------------
__global__ void lbp_kernel(const float* __restrict__ mo,
                           const float* __restrict__ lb,
                           unsigned long long* __restrict__ maskbits) {
    int m = blockIdx.y;                    // image 0..15: even=pred, odd=mask
    int pix = blockIdx.x * blockDim.x + threadIdx.x;   // 0..262143
    int r = pix >> 9, c = pix & 511;
    int sample = m >> 1;
    const float* img = (m & 1) ? (lb + sample * NPIX) : (mo + sample * NPIX);
    float thr = (m & 1) ? 0.5f : 0.0f;     // sigmoid(x)>0.5 <=> x>0

    int rm = r - (r > 0), rp = r + (r < HH - 1);
    int cm = c - (c > 0), cp = c + (c < WW - 1);
    const float* rowm = img + rm * WW;
    const float* row0 = img + r  * WW;
    const float* rowp = img + rp * WW;

    bool bmm = rowm[cm] > thr, bm0 = rowm[c] > thr, bmp = rowm[cp] > thr;
    bool b0m = row0[cm] > thr, b00 = row0[c] > thr, b0p = row0[cp] > thr;
    bool bpm = rowp[cm] > thr, bp0 = rowp[c] > thr, bpp = rowp[cp] > thr;

    bool r0e = (r == 0), c0e = (c == 0);
    bool t2m = r0e ? bpm : b0m;    // B(row2, cm)
    bool t2c = r0e ? bp0 : b00;    // B(row2, c)
    bool t2p = r0e ? bpp : b0p;    // B(row2, cp)
    bool mc2 = c0e ? bmp : bm0;    // B(rm,  col2)
    bool tc2 = c0e ? t2p : t2c;    // B(row2,col2)
    bool zc2 = c0e ? b0p : b00;    // B(r,   col2)
    bool pc2 = c0e ? bpp : bp0;    // B(rp,  col2)

    unsigned bb =
        (b0p                     ?   1u : 0u)
      | ((bm0 & bmp & t2c & t2p) ?   2u : 0u)
      | (bm0                     ?   4u : 0u)
      | ((bmm & mc2 & t2m & tc2) ?   8u : 0u)
      | (b0m                     ?  16u : 0u)
      | ((b0m & zc2 & bpm & pc2) ?  32u : 0u)
      | (bp0                     ?  64u : 0u)
      | ((b0p & bp0 & bpp)       ? 128u : 0u);

    unsigned rol = ((bb << 1) | (bb >> 7)) & 0xFFu;
    int changes = __popc(bb ^ rol);
    int s = __popc(bb);
    bool maskbit = b00 && (changes <= 2) && (s < 5);   // lbp < THR(=5)

    unsigned long long w = __ballot(maskbit);
    if ((threadIdx.x & 63) == 0)
        maskbits[m * NWORDS + (pix >> 6)] = w;
}

// ---------------------------------------------------------------------------
// Kernel 2: stable row-major compaction to K=1024 packed points per image
// (unchanged)
// ---------------------------------------------------------------------------
__global__ void select_kernel(const unsigned long long* __restrict__ maskbits,
                              unsigned* __restrict__ ptsG) {
    __shared__ unsigned swv[4];
    int m = blockIdx.x, tid = threadIdx.x;
    int lane = tid & 63, wid = tid >> 6;

    for (int i = tid; i < KPTS; i += 256) ptsG[m * KPTS + i] = 0u;
    __syncthreads();

    unsigned running = 0;
    for (int ch = 0; ch < 16; ch++) {
        int w = ch * 256 + tid;
        unsigned long long word = maskbits[m * NWORDS + w];
        unsigned cnt = (unsigned)__popcll(word);

        unsigned x = cnt;                    // intra-wave inclusive scan
#pragma unroll
        for (int d = 1; d < 64; d <<= 1) {
            unsigned y = (unsigned)__shfl_up((int)x, d, 64);
            x += (lane >= d) ? y : 0u;
        }
        if (lane == 63) swv[wid] = x;
        __syncthreads();
        unsigned woff = 0, total = 0;
#pragma unroll
        for (int ww = 0; ww < 4; ww++) {
            unsigned t = swv[ww];
            total += t;
            woff += (ww < wid) ? t : 0u;
        }
        unsigned rank = running + woff + x - cnt;   // exclusive prefix
        while (word) {
            int b = __builtin_ctzll(word);
            word &= word - 1;
            if (rank < (unsigned)KPTS) {
                unsigned p = (unsigned)(w * 64 + b);
                unsigned rr = p >> 9, cc = p & 511u;
                ptsG[m * KPTS + rank] = (rr << 16) | cc;
            }
            rank++;
        }
        running += total;
        if (running >= (unsigned)KPTS) break;   // uniform -> safe
        __syncthreads();   // protect swv before next chunk
    }
}

// ---------------------------------------------------------------------------
// Kernel 3: single-wave Prim, TWO IMAGES PER WAVE, zero LDS, zero barriers.
// R0's 713 cy/iter = ~200 cy issue + ~500 cy hazard wait-states (DPP and
// v_readlane hazards on ONE dependent stream with nothing to fill them).
// Fix: both images' chains live in the same wave with disjoint registers,
// one basic block, NO volatile-asm pins (they are scheduler barriers) —
// the compiler interleaves the two independent streams so each fills the
// other's hazard slots. (This is R2's idea done right: R2 failed because a
// __syncthreads between the two images was a hard issue fence; here there
// is no barrier at all.) Biased indices iz are image-independent (shared).
// Per-image math (keys, idx tie-break, signed-min self-kill, edge encoding)
// is bit-identical to R0/R1 => identical extraction order; recover/final
// unchanged.
// ---------------------------------------------------------------------------
typedef short v2s __attribute__((ext_vector_type(2)));

__device__ __forceinline__ int dist2_packed(unsigned a, unsigned b) {
#if __has_builtin(__builtin_amdgcn_sdot2)
    v2s d = __builtin_bit_cast(v2s, a) - __builtin_bit_cast(v2s, b);
    return __builtin_amdgcn_sdot2(d, d, 0, false);
#else
    int dr = (int)(a >> 16) - (int)(b >> 16);
    int dc = (int)(a & 0xFFFFu) - (int)(b & 0xFFFFu);
    return __mul24(dr, dr) + __mul24(dc, dc);
#endif
}

__device__ __forceinline__ unsigned umin3(unsigned a, unsigned b, unsigned c) {
    unsigned t = a < b ? a : b;          // fuses to v_min3_u32
    return t < c ? t : c;
}

template <int CTRL>
__device__ __forceinline__ unsigned umin_dpp(unsigned x) {
    unsigned o = (unsigned)__builtin_amdgcn_update_dpp((int)x, (int)x, CTRL,
                                                       0xf, 0xf, false);
    return o < x ? o : x;
}

// biased key: coords pre-shifted <<5 so sdot2 gives d2<<10; acc = idx-1024
__device__ __forceinline__ unsigned mk_key(unsigned ps, unsigned qs, int izb) {
#if __has_builtin(__builtin_amdgcn_sdot2)
    v2s d = __builtin_bit_cast(v2s, ps) - __builtin_bit_cast(v2s, qs);
    return (unsigned)__builtin_amdgcn_sdot2(d, d, izb, false);
#else
    int dr = (int)(short)(ps >> 16) - (int)(short)(qs >> 16);
    int dc = (int)(short)(ps & 0xFFFFu) - (int)(short)(qs & 0xFFFFu);
    return (unsigned)(dr * dr + dc * dc + izb);
#endif
}

// uniform select of points[wslot][.] from 16 replicated regs, prefix P,
// scalar bools B0..B3 (wslot bits) — same idiom as R0/R1
#define SEL16B(P, B0, B1, B2, B3, res)                                    \
    { unsigned _a0 = B0 ? P##1  : P##0;                                   \
      unsigned _a1 = B0 ? P##3  : P##2;                                   \
      unsigned _a2 = B0 ? P##5  : P##4;                                   \
      unsigned _a3 = B0 ? P##7  : P##6;                                   \
      unsigned _a4 = B0 ? P##9  : P##8;                                   \
      unsigned _a5 = B0 ? P##11 : P##10;                                  \
      unsigned _a6 = B0 ? P##13 : P##12;                                  \
      unsigned _a7 = B0 ? P##15 : P##14;                                  \
      unsigned _c0 = B1 ? _a1 : _a0;                                      \
      unsigned _c1 = B1 ? _a3 : _a2;                                      \
      unsigned _c2 = B1 ? _a5 : _a4;                                      \
      unsigned _c3 = B1 ? _a7 : _a6;                                      \
      unsigned _e0 = B2 ? _c1 : _c0;                                      \
      unsigned _e1 = B2 ? _c3 : _c2;                                      \
      res = B3 ? _e1 : _e0; }

// init one slot for BOTH images (iz shared — image-independent)
#define SLOT_INIT2(s)                                                     \
    iz##s = ((s << 6) | lane) - 1024;                                     \
    pX##s = baseX[(s << 6) | lane] << 5;                                  \
    kX##s = mk_key(pX##s, pt0sX, iz##s);                                  \
    pY##s = baseY[(s << 6) | lane] << 5;                                  \
    kY##s = mk_key(pY##s, pt0sY, iz##s);

// decrease-key both images, one slot (signed min: dead stays dead;
// extracted slot self-kills via negative self-distance key)
#define UPD2(s)                                                           \
    { unsigned _nX = mk_key(pX##s, pjsX, iz##s);                          \
      kX##s = (unsigned)min((int)kX##s, (int)_nX);                        \
      unsigned _nY = mk_key(pY##s, pjsY, iz##s);                          \
      kY##s = (unsigned)min((int)kY##s, (int)_nY); }

// in-lane min over 16 slot keys, prefix K
#define MIN16(K, res)                                                     \
    { unsigned _m0 = umin3(K##0, K##1, K##2);                             \
      unsigned _m1 = umin3(K##3, K##4, K##5);                             \
      unsigned _m2 = umin3(K##6, K##7, K##8);                             \
      unsigned _m3 = umin3(K##9, K##10, K##11);                           \
      unsigned _m4 = umin3(K##12, K##13, K##14);                          \
      unsigned _ra = umin3(_m0, _m1, _m2);                                \
      unsigned _rb = umin3(_m3, _m4, K##15);                              \
      res = _ra < _rb ? _ra : _rb; }

__global__ __launch_bounds__(64, 1) void mst_kernel(const unsigned* __restrict__ ptsG,
                                                    unsigned* __restrict__ edgesG) {
    int lane = threadIdx.x;              // 0..63
    int b = blockIdx.x;                  // 0..7
    const unsigned* baseX = ptsG + (2 * b)     * KPTS;
    const unsigned* baseY = ptsG + (2 * b + 1) * KPTS;
    unsigned pt0sX = baseX[0] << 5;      // uniform self point 0
    unsigned pt0sY = baseY[0] << 5;

    unsigned pX0,pX1,pX2,pX3,pX4,pX5,pX6,pX7,pX8,pX9,pX10,pX11,pX12,pX13,pX14,pX15;
    unsigned pY0,pY1,pY2,pY3,pY4,pY5,pY6,pY7,pY8,pY9,pY10,pY11,pY12,pY13,pY14,pY15;
    unsigned kX0,kX1,kX2,kX3,kX4,kX5,kX6,kX7,kX8,kX9,kX10,kX11,kX12,kX13,kX14,kX15;
    unsigned kY0,kY1,kY2,kY3,kY4,kY5,kY6,kY7,kY8,kY9,kY10,kY11,kY12,kY13,kY14,kY15;
    int      iz0,iz1,iz2,iz3,iz4,iz5,iz6,iz7,iz8,iz9,iz10,iz11,iz12,iz13,iz14,iz15;

    SLOT_INIT2(0)  SLOT_INIT2(1)  SLOT_INIT2(2)  SLOT_INIT2(3)
    SLOT_INIT2(4)  SLOT_INIT2(5)  SLOT_INIT2(6)  SLOT_INIT2(7)
    SLOT_INIT2(8)  SLOT_INIT2(9)  SLOT_INIT2(10) SLOT_INIT2(11)
    SLOT_INIT2(12) SLOT_INIT2(13) SLOT_INIT2(14) SLOT_INIT2(15)

    unsigned* eoutX = edgesG + (2 * b)     * KPTS;
    unsigned* eoutY = edgesG + (2 * b + 1) * KPTS;

    unsigned rX, rY;
    MIN16(kX, rX);
    MIN16(kY, rY);

    unsigned accX = 0, accY = 0;     // per-lane edge accumulators

#pragma unroll 1
    for (int chk = 0; chk < 16; chk++) {
        int tmax = (chk < 15) ? 64 : 63;     // 15*64 + 63 = 1023 iterations
#pragma unroll 1
        for (int t = 0; t < tmax; t++) {
            // ---- interleaved wave-64 min: 4 DPP row-folds each ----
            rX = umin_dpp<0x111>(rX);  rY = umin_dpp<0x111>(rY);
            rX = umin_dpp<0x112>(rX);  rY = umin_dpp<0x112>(rY);
            rX = umin_dpp<0x114>(rX);  rY = umin_dpp<0x114>(rY);
            rX = umin_dpp<0x118>(rX);  rY = umin_dpp<0x118>(rY);
            unsigned q0X = (unsigned)__builtin_amdgcn_readlane((int)rX, 15);
            unsigned q0Y = (unsigned)__builtin_amdgcn_readlane((int)rY, 15);
            unsigned q1X = (unsigned)__builtin_amdgcn_readlane((int)rX, 31);
            unsigned q1Y = (unsigned)__builtin_amdgcn_readlane((int)rY, 31);
            unsigned q2X = (unsigned)__builtin_amdgcn_readlane((int)rX, 47);
            unsigned q2Y = (unsigned)__builtin_amdgcn_readlane((int)rY, 47);
            unsigned q3X = (unsigned)__builtin_amdgcn_readlane((int)rX, 63);
            unsigned q3Y = (unsigned)__builtin_amdgcn_readlane((int)rY, 63);
            unsigned waX = q0X < q1X ? q0X : q1X;
            unsigned waY = q0Y < q1Y ? q0Y : q1Y;
            unsigned wbX = q2X < q3X ? q2X : q3X;
            unsigned wbY = q2Y < q3Y ? q2Y : q3Y;
            unsigned wkX = (waX < wbX ? waX : wbX) + 1024u;   // scalar
            unsigned wkY = (waY < wbY ? waY : wbY) + 1024u;

            unsigned jX = wkX & 1023u, jY = wkY & 1023u;
            int wsX = (int)(jX >> 6), wlX = (int)(jX & 63u);
            int wsY = (int)(jY >> 6), wlY = (int)(jY & 63u);

            // ---- pj from register file: SEL16 + readlane, both images ----
            bool bX0 = (wsX & 1) != 0, bX1 = (wsX & 2) != 0;
            bool bX2 = (wsX & 4) != 0, bX3 = (wsX & 8) != 0;
            bool bY0 = (wsY & 1) != 0, bY1 = (wsY & 2) != 0;
            bool bY2 = (wsY & 4) != 0, bY3 = (wsY & 8) != 0;
            unsigned selX, selY;
            SEL16B(pX, bX0, bX1, bX2, bX3, selX);
            SEL16B(pY, bY0, bY1, bY2, bY3, selY);
            unsigned pjsX = (unsigned)__builtin_amdgcn_readlane((int)selX, wlX);
            unsigned pjsY = (unsigned)__builtin_amdgcn_readlane((int)selY, wlY);

            // ---- edge record: cndmask accumulate into lane t ----
            accX = (lane == t) ? wkX : accX;
            accY = (lane == t) ? wkY : accY;

            // ---- decrease-key; extracted slots self-kill (d2=0 -> neg) ----
            UPD2(0)  UPD2(1)  UPD2(2)  UPD2(3)
            UPD2(4)  UPD2(5)  UPD2(6)  UPD2(7)
            UPD2(8)  UPD2(9)  UPD2(10) UPD2(11)
            UPD2(12) UPD2(13) UPD2(14) UPD2(15)

            MIN16(kX, rX);               // next iteration's per-lane mins
            MIN16(kY, rY);
        }
        // full-wave coalesced batch stores; chk=15 lane63 writes stale
        // eout[1023] (never read by recover_kernel).
        eoutX[(chk << 6) + lane] = accX;
        eoutY[(chk << 6) + lane] = accY;
    }
}

// ---------------------------------------------------------------------------
// Kernel 4 (phase 2): recover src per edge + per-edge (Dp-Dm)^2. (unchanged)
// ---------------------------------------------------------------------------
__global__ void recover_kernel(const unsigned* __restrict__ ptsG,
                               const unsigned* __restrict__ edgesG,
                               float* __restrict__ contrib) {
    __shared__ unsigned sS[KPTS];
    __shared__ unsigned sO[KPTS];
    __shared__ unsigned short sT[KPTS];   // extraction time + 1 (0 = root)
    int g = blockIdx.x, m = blockIdx.y;
    int tid = threadIdx.x;
    int partner = m ^ 1;

    for (int i = tid; i < KPTS; i += 256) {
        sS[i] = ptsG[m * KPTS + i];
        sO[i] = ptsG[partner * KPTS + i];
    }
    for (int e = tid; e < KPTS - 1; e += 256) {
        unsigned wkk = edgesG[m * KPTS + e];
        sT[wkk & 1023u] = (unsigned short)(e + 1);
    }
    if (tid == 0) sT[0] = 0;
    __syncthreads();

    int lane = tid & 63, w = tid >> 6;
    for (int k = 0; k < 16; k++) {
        int e = g * 64 + w * 16 + k;
        if (e >= KPTS - 1) break;            // only e=1023 (g=15,w=3,k=15)
        unsigned wk = edgesG[m * KPTS + e];
        unsigned j = wk & 1023u;
        unsigned d2p = wk >> 10;
        unsigned pj = sS[j];
        unsigned te1 = (unsigned)(e + 1);

        unsigned best = 0xFFFFFFFFu;
#pragma unroll
        for (int i = 0; i < 16; i++) {
            int v = i * 64 + lane;
            unsigned pv = sS[v];
            int d2 = dist2_packed(pv, pj);
            unsigned tv1 = (unsigned)sT[v];
            bool qual = ((unsigned)d2 == d2p) && (tv1 < te1);
            unsigned cand = qual ? ((tv1 << 10) | (unsigned)v) : 0xFFFFFFFFu;
            best = cand < best ? cand : best;
        }
#pragma unroll
        for (int dd = 32; dd; dd >>= 1) {
            unsigned o = (unsigned)__shfl_xor((int)best, dd, 64);
            best = o < best ? o : best;
        }
        unsigned vsrc = best & 1023u;
        if (lane == 0) {
            unsigned oj = sO[j], os = sO[vsrc];
            float Dp = __fsqrt_rn((float)d2p);
            float Dm = __fsqrt_rn((float)dist2_packed(oj, os));
            float diff = Dp - Dm;
            contrib[m * (KPTS - 1) + e] = diff * diff;
        }
    }
}

// ---------------------------------------------------------------------------
// Kernel 5: per-image f64 sum (extraction order, deterministic) -> loss
// (unchanged)
// ---------------------------------------------------------------------------
__global__ void final_kernel(const float* __restrict__ contrib,
                             float* __restrict__ out) {
    __shared__ double part[NIMG];
    int t = threadIdx.x;
    if (t < NIMG) {
        double s = 0.0;
        for (int e = 0; e < KPTS - 1; e++)
            s += (double)contrib[t * (KPTS - 1) + e];
        part[t] = sqrt(s);
    }
    __syncthreads();
    if (t == 0) {
        double tot = 0.0;
        for (int i = 0; i < NIMG; i++) tot += part[i];
        out[0] = (float)(0.1 * tot / 8.0);
    }
}

// ---------------------------------------------------------------------------
// ws layout:
//   [0,512K)     maskbits (lbp->select), then DEAD:
//   [0,64K)      edgesG   (mst->recover)   — overlaps dead maskbits
//   [64K,128K)   contrib  (recover->final) — overlaps dead maskbits
//   [512K,576K)  ptsG     (select->mst/recover)
// ---------------------------------------------------------------------------
extern "C" void kernel_launch(void* const* d_in, const int* in_sizes, int n_in,
                              void* d_out, int out_size, void* d_ws, size_t ws_size,
                              hipStream_t stream) {
    const float* mo = (const float*)d_in[1];   // model_output
    const float* lb = (const float*)d_in[2];   // labels

    unsigned long long* maskbits = (unsigned long long*)d_ws;
    unsigned* edgesG = (unsigned*)d_ws;
    float* contrib = (float*)((char*)d_ws + (size_t)64 * 1024);
    unsigned* ptsG = (unsigned*)((char*)d_ws + (size_t)NIMG * NWORDS * 8);
    float* out = (float*)d_out;

    lbp_kernel<<<dim3(NPIX / 256, NIMG), 256, 0, stream>>>(mo, lb, maskbits);
    select_kernel<<<NIMG, 256, 0, stream>>>(maskbits, ptsG);
    mst_kernel<<<NIMG / 2, 64, 0, stream>>>(ptsG, edgesG);
    recover_kernel<<<dim3(16, NIMG), 256, 0, stream>>>(ptsG, edgesG, contrib);
    final_kernel<<<1, 64, 0, stream>>>(contrib, out);
}

// Round 9
// 410.404 us; speedup vs baseline: 1.7012x; 1.7012x over previous
//
#include <hip/hip_runtime.h>

#define HH 512
#define WW 512
#define NPIX (HH * WW)          // 262144
#define NIMG 16
#define KPTS 1024
#define NWORDS (NPIX / 64)      // 4096 u64 mask words per image

// ---------------------------------------------------------------------------
// Kernel 1: binarize + uniform LBP (P=8,R=1) — PURE BOOLEAN form.
// ---------------------------------------------------------------------------
__global__ void lbp_kernel(const float* __restrict__ mo,
                           const float* __restrict__ lb,
                           unsigned long long* __restrict__ maskbits) {
    int m = blockIdx.y;                    // image 0..15: even=pred, odd=mask
    int pix = blockIdx.x * blockDim.x + threadIdx.x;   // 0..262143
    int r = pix >> 9, c = pix & 511;
    int sample = m >> 1;
    const float* img = (m & 1) ? (lb + sample * NPIX) : (mo + sample * NPIX);
    float thr = (m & 1) ? 0.5f : 0.0f;     // sigmoid(x)>0.5 <=> x>0

    int rm = r - (r > 0), rp = r + (r < HH - 1);
    int cm = c - (c > 0), cp = c + (c < WW - 1);
    const float* rowm = img + rm * WW;
    const float* row0 = img + r  * WW;
    const float* rowp = img + rp * WW;

    bool bmm = rowm[cm] > thr, bm0 = rowm[c] > thr, bmp = rowm[cp] > thr;
    bool b0m = row0[cm] > thr, b00 = row0[c] > thr, b0p = row0[cp] > thr;
    bool bpm = rowp[cm] > thr, bp0 = rowp[c] > thr, bpp = rowp[cp] > thr;

    bool r0e = (r == 0), c0e = (c == 0);
    bool t2m = r0e ? bpm : b0m;    // B(row2, cm)
    bool t2c = r0e ? bp0 : b00;    // B(row2, c)
    bool t2p = r0e ? bpp : b0p;    // B(row2, cp)
    bool mc2 = c0e ? bmp : bm0;    // B(rm,  col2)
    bool tc2 = c0e ? t2p : t2c;    // B(row2,col2)
    bool zc2 = c0e ? b0p : b00;    // B(r,   col2)
    bool pc2 = c0e ? bpp : bp0;    // B(rp,  col2)

    unsigned bb =
        (b0p                     ?   1u : 0u)
      | ((bm0 & bmp & t2c & t2p) ?   2u : 0u)
      | (bm0                     ?   4u : 0u)
      | ((bmm & mc2 & t2m & tc2) ?   8u : 0u)
      | (b0m                     ?  16u : 0u)
      | ((b0m & zc2 & bpm & pc2) ?  32u : 0u)
      | (bp0                     ?  64u : 0u)
      | ((b0p & bp0 & bpp)       ? 128u : 0u);

    unsigned rol = ((bb << 1) | (bb >> 7)) & 0xFFu;
    int changes = __popc(bb ^ rol);
    int s = __popc(bb);
    bool maskbit = b00 && (changes <= 2) && (s < 5);   // lbp < THR(=5)

    unsigned long long w = __ballot(maskbit);
    if ((threadIdx.x & 63) == 0)
        maskbits[m * NWORDS + (pix >> 6)] = w;
}

// ---------------------------------------------------------------------------
// Kernel 2: stable row-major compaction to K=1024 packed points per image
// ---------------------------------------------------------------------------
__global__ void select_kernel(const unsigned long long* __restrict__ maskbits,
                              unsigned* __restrict__ ptsG) {
    __shared__ unsigned swv[4];
    int m = blockIdx.x, tid = threadIdx.x;
    int lane = tid & 63, wid = tid >> 6;

    for (int i = tid; i < KPTS; i += 256) ptsG[m * KPTS + i] = 0u;
    __syncthreads();

    unsigned running = 0;
    for (int ch = 0; ch < 16; ch++) {
        int w = ch * 256 + tid;
        unsigned long long word = maskbits[m * NWORDS + w];
        unsigned cnt = (unsigned)__popcll(word);

        unsigned x = cnt;                    // intra-wave inclusive scan
#pragma unroll
        for (int d = 1; d < 64; d <<= 1) {
            unsigned y = (unsigned)__shfl_up((int)x, d, 64);
            x += (lane >= d) ? y : 0u;
        }
        if (lane == 63) swv[wid] = x;
        __syncthreads();
        unsigned woff = 0, total = 0;
#pragma unroll
        for (int ww = 0; ww < 4; ww++) {
            unsigned t = swv[ww];
            total += t;
            woff += (ww < wid) ? t : 0u;
        }
        unsigned rank = running + woff + x - cnt;   // exclusive prefix
        while (word) {
            int b = __builtin_ctzll(word);
            word &= word - 1;
            if (rank < (unsigned)KPTS) {
                unsigned p = (unsigned)(w * 64 + b);
                unsigned rr = p >> 9, cc = p & 511u;
                ptsG[m * KPTS + rank] = (rr << 16) | cc;
            }
            rank++;
        }
        running += total;
        if (running >= (unsigned)KPTS) break;   // uniform -> safe
        __syncthreads();   // protect swv before next chunk
    }
}

// ---------------------------------------------------------------------------
// Kernel 3: 4-wave Prim per image — the R1 structure, restored bit-exact.
// Best measured across 9 structural variants (657 cy/iter, 280.8 µs):
// keys PARTITIONED (4 slots/wave), points REPLICATED per wave, per-iter
// {6-DPP wave min -> lane63 ds_write -> ONE barrier -> b128 broadcast read
// -> scalar decode -> SEL16 + readlane -> 4 decrease-keys}. All probed
// alternatives (spin ping-pong, ds_min/bpermute, two-extraction, dual-image
// ILP, VGPR-bool decode) regressed 40-600 cy/iter. Self-killing keys:
// k = (d2<<10) + idx - 1024 via sdot2 on <<5-shifted coords; live >= 0,
// dead < 0; reduce = unsigned min, update = signed min.
// ---------------------------------------------------------------------------
typedef short v2s __attribute__((ext_vector_type(2)));
typedef unsigned u32x4 __attribute__((ext_vector_type(4)));

__device__ __forceinline__ int dist2_packed(unsigned a, unsigned b) {
#if __has_builtin(__builtin_amdgcn_sdot2)
    v2s d = __builtin_bit_cast(v2s, a) - __builtin_bit_cast(v2s, b);
    return __builtin_amdgcn_sdot2(d, d, 0, false);
#else
    int dr = (int)(a >> 16) - (int)(b >> 16);
    int dc = (int)(a & 0xFFFFu) - (int)(b & 0xFFFFu);
    return __mul24(dr, dr) + __mul24(dc, dc);
#endif
}

template <int CTRL>
__device__ __forceinline__ unsigned umin_dpp(unsigned x) {
    unsigned o = (unsigned)__builtin_amdgcn_update_dpp((int)x, (int)x, CTRL,
                                                       0xf, 0xf, false);
    return o < x ? o : x;
}

// full-wave unsigned-min; result valid in lane 63 only.
__device__ __forceinline__ unsigned wave_min_to_lane63(unsigned x) {
    x = umin_dpp<0x111>(x);   // row_shr:1
    x = umin_dpp<0x112>(x);   // row_shr:2
    x = umin_dpp<0x114>(x);   // row_shr:4
    x = umin_dpp<0x118>(x);   // row_shr:8  -> lane15 of each 16-row
    x = umin_dpp<0x142>(x);   // row_bcast:15
    x = umin_dpp<0x143>(x);   // row_bcast:31 -> lane63 = wave min
    return x;
}

__device__ __forceinline__ unsigned umin3(unsigned a, unsigned b, unsigned c) {
    unsigned t = a < b ? a : b;          // fuses to v_min3_u32
    return t < c ? t : c;
}

// biased key: coords pre-shifted <<5 so sdot2 gives d2<<10; acc = idx-1024
__device__ __forceinline__ unsigned mk_key(unsigned ps, unsigned qs, int izb) {
#if __has_builtin(__builtin_amdgcn_sdot2)
    v2s d = __builtin_bit_cast(v2s, ps) - __builtin_bit_cast(v2s, qs);
    return (unsigned)__builtin_amdgcn_sdot2(d, d, izb, false);
#else
    int dr = (int)(short)(ps >> 16) - (int)(short)(qs >> 16);
    int dc = (int)(short)(ps & 0xFFFFu) - (int)(short)(qs & 0xFFFFu);
    return (unsigned)(dr * dr + dc * dc + izb);
#endif
}

// uniform select of points[wslot][wlane] from 16 replicated regs
#define SEL16(P, res)                                                     \
    { unsigned _a0 = b0 ? P##1  : P##0;                                   \
      unsigned _a1 = b0 ? P##3  : P##2;                                   \
      unsigned _a2 = b0 ? P##5  : P##4;                                   \
      unsigned _a3 = b0 ? P##7  : P##6;                                   \
      unsigned _a4 = b0 ? P##9  : P##8;                                   \
      unsigned _a5 = b0 ? P##11 : P##10;                                  \
      unsigned _a6 = b0 ? P##13 : P##12;                                  \
      unsigned _a7 = b0 ? P##15 : P##14;                                  \
      unsigned _c0 = b1 ? _a1 : _a0;                                      \
      unsigned _c1 = b1 ? _a3 : _a2;                                      \
      unsigned _c2 = b1 ? _a5 : _a4;                                      \
      unsigned _c3 = b1 ? _a7 : _a6;                                      \
      unsigned _e0 = b2 ? _c1 : _c0;                                      \
      unsigned _e1 = b2 ? _c3 : _c2;                                      \
      res = b3 ? _e1 : _e0; }

#define LOADP(P, B)                                                       \
    unsigned P##0  = B[( 0 << 6) | lane] << 5;                            \
    unsigned P##1  = B[( 1 << 6) | lane] << 5;                            \
    unsigned P##2  = B[( 2 << 6) | lane] << 5;                            \
    unsigned P##3  = B[( 3 << 6) | lane] << 5;                            \
    unsigned P##4  = B[( 4 << 6) | lane] << 5;                            \
    unsigned P##5  = B[( 5 << 6) | lane] << 5;                            \
    unsigned P##6  = B[( 6 << 6) | lane] << 5;                            \
    unsigned P##7  = B[( 7 << 6) | lane] << 5;                            \
    unsigned P##8  = B[( 8 << 6) | lane] << 5;                            \
    unsigned P##9  = B[( 9 << 6) | lane] << 5;                            \
    unsigned P##10 = B[(10 << 6) | lane] << 5;                            \
    unsigned P##11 = B[(11 << 6) | lane] << 5;                            \
    unsigned P##12 = B[(12 << 6) | lane] << 5;                            \
    unsigned P##13 = B[(13 << 6) | lane] << 5;                            \
    unsigned P##14 = B[(14 << 6) | lane] << 5;                            \
    unsigned P##15 = B[(15 << 6) | lane] << 5;

__global__ __launch_bounds__(256, 1) void mst_kernel(const unsigned* __restrict__ ptsG,
                                                     unsigned* __restrict__ edgesG) {
    __shared__ __align__(16) unsigned xm[2][4];   // parity double-buffer
    int tid = threadIdx.x;
    int lane = tid & 63, wid = tid >> 6;
    int m = blockIdx.x;
    const unsigned* base = ptsG + m * KPTS;
    unsigned pt0s = base[0] << 5;    // self point 0, shifted (uniform)

    // replicated full point set (read-only; feeds SEL16 in every wave)
    LOADP(p, base)

    // this wave's 4 owned key slots: global slot = wid*4 + sl
    int oi0 = (((wid * 4 + 0) << 6) | lane) - 1024;
    int oi1 = (((wid * 4 + 1) << 6) | lane) - 1024;
    int oi2 = (((wid * 4 + 2) << 6) | lane) - 1024;
    int oi3 = (((wid * 4 + 3) << 6) | lane) - 1024;
    unsigned oq0 = base[((wid * 4 + 0) << 6) | lane] << 5;
    unsigned oq1 = base[((wid * 4 + 1) << 6) | lane] << 5;
    unsigned oq2 = base[((wid * 4 + 2) << 6) | lane] << 5;
    unsigned oq3 = base[((wid * 4 + 3) << 6) | lane] << 5;
    unsigned ok0 = mk_key(oq0, pt0s, oi0);   // node0 self-kills
    unsigned ok1 = mk_key(oq1, pt0s, oi1);
    unsigned ok2 = mk_key(oq2, pt0s, oi2);
    unsigned ok3 = mk_key(oq3, pt0s, oi3);

    unsigned* eout = edgesG + m * KPTS;
    unsigned r3i = umin3(ok0, ok1, ok2);
    unsigned rk = r3i < ok3 ? r3i : ok3;    // per-lane min over own 4 slots

    unsigned acc = 0;                // per-lane edge accumulator (batch of 64)
    int par = 0;

    for (int chk = 0; chk < 16; chk++) {
        int tmax = (chk < 15) ? 64 : 63;     // 15*64 + 63 = 1023 iterations
        for (int t = 0; t < tmax; t++) {
            // ---- per-wave reduce (6 DPP mins, result in lane63) ----
            unsigned wmin = wave_min_to_lane63(rk);
            if (lane == 63) xm[par][wid] = wmin;
            __syncthreads();

            // ---- cross-wave combine: broadcast b128 read of 4 minima ----
            u32x4 xv = *reinterpret_cast<const u32x4*>(&xm[par][0]);
            unsigned vm = umin3(xv.x, xv.y, xv.z);
            vm = vm < xv.w ? vm : xv.w;
            unsigned wk = (unsigned)__builtin_amdgcn_readfirstlane((int)vm) + 1024u;
            par ^= 1;

            unsigned j = wk & 1023u;
            int wslot = (int)(j >> 6);
            int wlane = (int)(j & 63u);

            // ---- pj (shifted coords) from replicated regs: SEL16+readlane --
            bool b0 = (wslot & 1) != 0, b1 = (wslot & 2) != 0;
            bool b2 = (wslot & 4) != 0, b3 = (wslot & 8) != 0;
            unsigned selPay;
            SEL16(p, selPay);
            unsigned pjs = (unsigned)__builtin_amdgcn_readlane((int)selPay, wlane);

            // ---- edge record: cndmask accumulate into lane t ----
            acc = (lane == t) ? wk : acc;

            // ---- decrease-key on own 4 slots; extracted slot self-kills ----
            { unsigned nk = mk_key(oq0, pjs, oi0);
              ok0 = (unsigned)min((int)ok0, (int)nk); }
            { unsigned nk = mk_key(oq1, pjs, oi1);
              ok1 = (unsigned)min((int)ok1, (int)nk); }
            { unsigned nk = mk_key(oq2, pjs, oi2);
              ok2 = (unsigned)min((int)ok2, (int)nk); }
            { unsigned nk = mk_key(oq3, pjs, oi3);
              ok3 = (unsigned)min((int)ok3, (int)nk); }
            unsigned r3 = umin3(ok0, ok1, ok2);
            rk = r3 < ok3 ? r3 : ok3;       // next iteration's per-lane min
        }
        // wave 0 does the full-wave coalesced batch store; chk=15 lane63
        // writes eout[1023] (stale value) which is never read downstream.
        if (wid == 0) eout[(chk << 6) + lane] = acc;
    }
}

// ---------------------------------------------------------------------------
// Kernel 4 (phase 2): recover src per edge + per-edge (Dp-Dm)^2.
// ---------------------------------------------------------------------------
__global__ void recover_kernel(const unsigned* __restrict__ ptsG,
                               const unsigned* __restrict__ edgesG,
                               float* __restrict__ contrib) {
    __shared__ unsigned sS[KPTS];
    __shared__ unsigned sO[KPTS];
    __shared__ unsigned short sT[KPTS];   // extraction time + 1 (0 = root)
    int g = blockIdx.x, m = blockIdx.y;
    int tid = threadIdx.x;
    int partner = m ^ 1;

    for (int i = tid; i < KPTS; i += 256) {
        sS[i] = ptsG[m * KPTS + i];
        sO[i] = ptsG[partner * KPTS + i];
    }
    for (int e = tid; e < KPTS - 1; e += 256) {
        unsigned wkk = edgesG[m * KPTS + e];
        sT[wkk & 1023u] = (unsigned short)(e + 1);
    }
    if (tid == 0) sT[0] = 0;
    __syncthreads();

    int lane = tid & 63, w = tid >> 6;
    for (int k = 0; k < 16; k++) {
        int e = g * 64 + w * 16 + k;
        if (e >= KPTS - 1) break;            // only e=1023 (g=15,w=3,k=15)
        unsigned wk = edgesG[m * KPTS + e];
        unsigned j = wk & 1023u;
        unsigned d2p = wk >> 10;
        unsigned pj = sS[j];
        unsigned te1 = (unsigned)(e + 1);

        unsigned best = 0xFFFFFFFFu;
#pragma unroll
        for (int i = 0; i < 16; i++) {
            int v = i * 64 + lane;
            unsigned pv = sS[v];
            int d2 = dist2_packed(pv, pj);
            unsigned tv1 = (unsigned)sT[v];
            bool qual = ((unsigned)d2 == d2p) && (tv1 < te1);
            unsigned cand = qual ? ((tv1 << 10) | (unsigned)v) : 0xFFFFFFFFu;
            best = cand < best ? cand : best;
        }
#pragma unroll
        for (int dd = 32; dd; dd >>= 1) {
            unsigned o = (unsigned)__shfl_xor((int)best, dd, 64);
            best = o < best ? o : best;
        }
        unsigned vsrc = best & 1023u;
        if (lane == 0) {
            unsigned oj = sO[j], os = sO[vsrc];
            float Dp = __fsqrt_rn((float)d2p);
            float Dm = __fsqrt_rn((float)dist2_packed(oj, os));
            float diff = Dp - Dm;
            contrib[m * (KPTS - 1) + e] = diff * diff;
        }
    }
}

// ---------------------------------------------------------------------------
// Kernel 5: per-image f64 sum (extraction order, deterministic) -> loss
// ---------------------------------------------------------------------------
__global__ void final_kernel(const float* __restrict__ contrib,
                             float* __restrict__ out) {
    __shared__ double part[NIMG];
    int t = threadIdx.x;
    if (t < NIMG) {
        double s = 0.0;
        for (int e = 0; e < KPTS - 1; e++)
            s += (double)contrib[t * (KPTS - 1) + e];
        part[t] = sqrt(s);
    }
    __syncthreads();
    if (t == 0) {
        double tot = 0.0;
        for (int i = 0; i < NIMG; i++) tot += part[i];
        out[0] = (float)(0.1 * tot / 8.0);
    }
}

// ---------------------------------------------------------------------------
// ws layout:
//   [0,512K)     maskbits (lbp->select), then DEAD:
//   [0,64K)      edgesG   (mst->recover)   — overlaps dead maskbits
//   [64K,128K)   contrib  (recover->final) — overlaps dead maskbits
//   [512K,576K)  ptsG     (select->mst/recover)
// ---------------------------------------------------------------------------
extern "C" void kernel_launch(void* const* d_in, const int* in_sizes, int n_in,
                              void* d_out, int out_size, void* d_ws, size_t ws_size,
                              hipStream_t stream) {
    const float* mo = (const float*)d_in[1];   // model_output
    const float* lb = (const float*)d_in[2];   // labels

    unsigned long long* maskbits = (unsigned long long*)d_ws;
    unsigned* edgesG = (unsigned*)d_ws;
    float* contrib = (float*)((char*)d_ws + (size_t)64 * 1024);
    unsigned* ptsG = (unsigned*)((char*)d_ws + (size_t)NIMG * NWORDS * 8);
    float* out = (float*)d_out;

    lbp_kernel<<<dim3(NPIX / 256, NIMG), 256, 0, stream>>>(mo, lb, maskbits);
    select_kernel<<<NIMG, 256, 0, stream>>>(maskbits, ptsG);
    mst_kernel<<<NIMG, 256, 0, stream>>>(ptsG, edgesG);
    recover_kernel<<<dim3(16, NIMG), 256, 0, stream>>>(ptsG, edgesG, contrib);
    final_kernel<<<1, 64, 0, stream>>>(contrib, out);
}

// Round 10
// 406.408 us; speedup vs baseline: 1.7179x; 1.0098x over previous
//
#include <hip/hip_runtime.h>

#define HH 512
#define WW 512
#define NPIX (HH * WW)          // 262144
#define NIMG 16
#define KPTS 1024
#define NWORDS (NPIX / 64)      // 4096 u64 mask words per image
#define IMGW 8192               // u32 words per image region in ws (32 KB)

// ---------------------------------------------------------------------------
// Kernel 1: binarize + uniform LBP (P=8,R=1) — PURE BOOLEAN form. (unchanged)
// ---------------------------------------------------------------------------
__global__ void lbp_kernel(const float* __restrict__ mo,
                           const float* __restrict__ lb,
                           unsigned long long* __restrict__ maskbits) {
    int m = blockIdx.y;                    // image 0..15: even=pred, odd=mask
    int pix = blockIdx.x * blockDim.x + threadIdx.x;   // 0..262143
    int r = pix >> 9, c = pix & 511;
    int sample = m >> 1;
    const float* img = (m & 1) ? (lb + sample * NPIX) : (mo + sample * NPIX);
    float thr = (m & 1) ? 0.5f : 0.0f;     // sigmoid(x)>0.5 <=> x>0

    int rm = r - (r > 0), rp = r + (r < HH - 1);
    int cm = c - (c > 0), cp = c + (c < WW - 1);
    const float* rowm = img + rm * WW;
    const float* row0 = img + r  * WW;
    const float* rowp = img + rp * WW;

    bool bmm = rowm[cm] > thr, bm0 = rowm[c] > thr, bmp = rowm[cp] > thr;
    bool b0m = row0[cm] > thr, b00 = row0[c] > thr, b0p = row0[cp] > thr;
    bool bpm = rowp[cm] > thr, bp0 = rowp[c] > thr, bpp = rowp[cp] > thr;

    bool r0e = (r == 0), c0e = (c == 0);
    bool t2m = r0e ? bpm : b0m;    // B(row2, cm)
    bool t2c = r0e ? bp0 : b00;    // B(row2, c)
    bool t2p = r0e ? bpp : b0p;    // B(row2, cp)
    bool mc2 = c0e ? bmp : bm0;    // B(rm,  col2)
    bool tc2 = c0e ? t2p : t2c;    // B(row2,col2)
    bool zc2 = c0e ? b0p : b00;    // B(r,   col2)
    bool pc2 = c0e ? bpp : bp0;    // B(rp,  col2)

    unsigned bb =
        (b0p                     ?   1u : 0u)
      | ((bm0 & bmp & t2c & t2p) ?   2u : 0u)
      | (bm0                     ?   4u : 0u)
      | ((bmm & mc2 & t2m & tc2) ?   8u : 0u)
      | (b0m                     ?  16u : 0u)
      | ((b0m & zc2 & bpm & pc2) ?  32u : 0u)
      | (bp0                     ?  64u : 0u)
      | ((b0p & bp0 & bpp)       ? 128u : 0u);

    unsigned rol = ((bb << 1) | (bb >> 7)) & 0xFFu;
    int changes = __popc(bb ^ rol);
    int s = __popc(bb);
    bool maskbit = b00 && (changes <= 2) && (s < 5);   // lbp < THR(=5)

    unsigned long long w = __ballot(maskbit);
    if ((threadIdx.x & 63) == 0)
        maskbits[m * NWORDS + (pix >> 6)] = w;
}

// ---------------------------------------------------------------------------
// Kernel 2 (FUSED select + mst): grid 16 x 256 — identical shapes, so the
// two former kernels fuse into one launch (pipeline 5 -> 4 launches).
//   Phase A (select): stable row-major compaction to K=1024 packed points,
//     written BOTH to global ptsG (for recover) and an LDS copy sP (for
//     phase B). Identical logic to the previous select_kernel.
//   Phase B (mst): the proven R1 structure, bit-exact (657 cy/iter best of
//     9 measured variants), points loaded from sP instead of global.
// WS RACE DISCIPLINE: edges for image m now live INSIDE image m's own 32KB
// maskbit region (u32 stride IMGW=8192/image, words [0,1024)). Those bytes
// are maskbit chunks 0-1 of image m, consumed by the SAME block's select
// phase strictly before its mst phase writes them -> no cross-block
// conflict, no dispatch-order assumptions (G16). contrib lives at words
// [2048,3071) of the same region, written only by recover (next kernel).
// ---------------------------------------------------------------------------
typedef short v2s __attribute__((ext_vector_type(2)));
typedef unsigned u32x4 __attribute__((ext_vector_type(4)));

__device__ __forceinline__ int dist2_packed(unsigned a, unsigned b) {
#if __has_builtin(__builtin_amdgcn_sdot2)
    v2s d = __builtin_bit_cast(v2s, a) - __builtin_bit_cast(v2s, b);
    return __builtin_amdgcn_sdot2(d, d, 0, false);
#else
    int dr = (int)(a >> 16) - (int)(b >> 16);
    int dc = (int)(a & 0xFFFFu) - (int)(b & 0xFFFFu);
    return __mul24(dr, dr) + __mul24(dc, dc);
#endif
}

template <int CTRL>
__device__ __forceinline__ unsigned umin_dpp(unsigned x) {
    unsigned o = (unsigned)__builtin_amdgcn_update_dpp((int)x, (int)x, CTRL,
                                                       0xf, 0xf, false);
    return o < x ? o : x;
}

// full-wave unsigned-min; result valid in lane 63 only.
__device__ __forceinline__ unsigned wave_min_to_lane63(unsigned x) {
    x = umin_dpp<0x111>(x);   // row_shr:1
    x = umin_dpp<0x112>(x);   // row_shr:2
    x = umin_dpp<0x114>(x);   // row_shr:4
    x = umin_dpp<0x118>(x);   // row_shr:8  -> lane15 of each 16-row
    x = umin_dpp<0x142>(x);   // row_bcast:15
    x = umin_dpp<0x143>(x);   // row_bcast:31 -> lane63 = wave min
    return x;
}

__device__ __forceinline__ unsigned umin3(unsigned a, unsigned b, unsigned c) {
    unsigned t = a < b ? a : b;          // fuses to v_min3_u32
    return t < c ? t : c;
}

// biased key: coords pre-shifted <<5 so sdot2 gives d2<<10; acc = idx-1024
__device__ __forceinline__ unsigned mk_key(unsigned ps, unsigned qs, int izb) {
#if __has_builtin(__builtin_amdgcn_sdot2)
    v2s d = __builtin_bit_cast(v2s, ps) - __builtin_bit_cast(v2s, qs);
    return (unsigned)__builtin_amdgcn_sdot2(d, d, izb, false);
#else
    int dr = (int)(short)(ps >> 16) - (int)(short)(qs >> 16);
    int dc = (int)(short)(ps & 0xFFFFu) - (int)(short)(qs & 0xFFFFu);
    return (unsigned)(dr * dr + dc * dc + izb);
#endif
}

// uniform select of points[wslot][wlane] from 16 replicated regs
#define SEL16(P, res)                                                     \
    { unsigned _a0 = b0 ? P##1  : P##0;                                   \
      unsigned _a1 = b0 ? P##3  : P##2;                                   \
      unsigned _a2 = b0 ? P##5  : P##4;                                   \
      unsigned _a3 = b0 ? P##7  : P##6;                                   \
      unsigned _a4 = b0 ? P##9  : P##8;                                   \
      unsigned _a5 = b0 ? P##11 : P##10;                                  \
      unsigned _a6 = b0 ? P##13 : P##12;                                  \
      unsigned _a7 = b0 ? P##15 : P##14;                                  \
      unsigned _c0 = b1 ? _a1 : _a0;                                      \
      unsigned _c1 = b1 ? _a3 : _a2;                                      \
      unsigned _c2 = b1 ? _a5 : _a4;                                      \
      unsigned _c3 = b1 ? _a7 : _a6;                                      \
      unsigned _e0 = b2 ? _c1 : _c0;                                      \
      unsigned _e1 = b2 ? _c3 : _c2;                                      \
      res = b3 ? _e1 : _e0; }

#define LOADP(P, B)                                                       \
    unsigned P##0  = B[( 0 << 6) | lane] << 5;                            \
    unsigned P##1  = B[( 1 << 6) | lane] << 5;                            \
    unsigned P##2  = B[( 2 << 6) | lane] << 5;                            \
    unsigned P##3  = B[( 3 << 6) | lane] << 5;                            \
    unsigned P##4  = B[( 4 << 6) | lane] << 5;                            \
    unsigned P##5  = B[( 5 << 6) | lane] << 5;                            \
    unsigned P##6  = B[( 6 << 6) | lane] << 5;                            \
    unsigned P##7  = B[( 7 << 6) | lane] << 5;                            \
    unsigned P##8  = B[( 8 << 6) | lane] << 5;                            \
    unsigned P##9  = B[( 9 << 6) | lane] << 5;                            \
    unsigned P##10 = B[(10 << 6) | lane] << 5;                            \
    unsigned P##11 = B[(11 << 6) | lane] << 5;                            \
    unsigned P##12 = B[(12 << 6) | lane] << 5;                            \
    unsigned P##13 = B[(13 << 6) | lane] << 5;                            \
    unsigned P##14 = B[(14 << 6) | lane] << 5;                            \
    unsigned P##15 = B[(15 << 6) | lane] << 5;

__global__ __launch_bounds__(256, 1) void selmst_kernel(
        const unsigned long long* __restrict__ maskbits,
        unsigned* __restrict__ ptsG,
        unsigned* __restrict__ wsW) {
    __shared__ unsigned sP[KPTS];                 // LDS copy of packed points
    __shared__ unsigned swv[4];
    __shared__ __align__(16) unsigned xm[2][4];   // parity double-buffer
    int tid = threadIdx.x;
    int lane = tid & 63, wid = tid >> 6;
    int m = blockIdx.x;

    // ================= Phase A: select (identical logic) =================
    unsigned* ptsOut = ptsG + m * KPTS;
    for (int i = tid; i < KPTS; i += 256) { ptsOut[i] = 0u; sP[i] = 0u; }
    __syncthreads();

    unsigned running = 0;
    for (int ch = 0; ch < 16; ch++) {
        int w = ch * 256 + tid;
        unsigned long long word = maskbits[m * NWORDS + w];
        unsigned cnt = (unsigned)__popcll(word);

        unsigned x = cnt;                    // intra-wave inclusive scan
#pragma unroll
        for (int d = 1; d < 64; d <<= 1) {
            unsigned y = (unsigned)__shfl_up((int)x, d, 64);
            x += (lane >= d) ? y : 0u;
        }
        if (lane == 63) swv[wid] = x;
        __syncthreads();
        unsigned woff = 0, total = 0;
#pragma unroll
        for (int ww = 0; ww < 4; ww++) {
            unsigned tt = swv[ww];
            total += tt;
            woff += (ww < wid) ? tt : 0u;
        }
        unsigned rank = running + woff + x - cnt;   // exclusive prefix
        while (word) {
            int bpos = __builtin_ctzll(word);
            word &= word - 1;
            if (rank < (unsigned)KPTS) {
                unsigned pv = (unsigned)(w * 64 + bpos);
                unsigned packed = ((pv >> 9) << 16) | (pv & 511u);
                ptsOut[rank] = packed;
                sP[rank] = packed;
            }
            rank++;
        }
        running += total;
        if (running >= (unsigned)KPTS) break;   // uniform -> safe
        __syncthreads();   // protect swv before next chunk
    }
    __syncthreads();       // sP complete before mst phase reads it

    // ============ Phase B: mst (R1 structure, points from LDS) ===========
    unsigned pt0s = sP[0] << 5;      // self point 0, shifted (uniform)
    LOADP(p, sP)                     // replicated point set from LDS

    // this wave's 4 owned key slots: global slot = wid*4 + sl
    int oi0 = (((wid * 4 + 0) << 6) | lane) - 1024;
    int oi1 = (((wid * 4 + 1) << 6) | lane) - 1024;
    int oi2 = (((wid * 4 + 2) << 6) | lane) - 1024;
    int oi3 = (((wid * 4 + 3) << 6) | lane) - 1024;
    unsigned oq0 = sP[((wid * 4 + 0) << 6) | lane] << 5;
    unsigned oq1 = sP[((wid * 4 + 1) << 6) | lane] << 5;
    unsigned oq2 = sP[((wid * 4 + 2) << 6) | lane] << 5;
    unsigned oq3 = sP[((wid * 4 + 3) << 6) | lane] << 5;
    unsigned ok0 = mk_key(oq0, pt0s, oi0);   // node0 self-kills
    unsigned ok1 = mk_key(oq1, pt0s, oi1);
    unsigned ok2 = mk_key(oq2, pt0s, oi2);
    unsigned ok3 = mk_key(oq3, pt0s, oi3);

    unsigned* eout = wsW + m * IMGW;     // image m's OWN region (see header)
    unsigned r3i = umin3(ok0, ok1, ok2);
    unsigned rk = r3i < ok3 ? r3i : ok3;    // per-lane min over own 4 slots

    unsigned acc = 0;                // per-lane edge accumulator (batch of 64)
    int par = 0;

    for (int chk = 0; chk < 16; chk++) {
        int tmax = (chk < 15) ? 64 : 63;     // 15*64 + 63 = 1023 iterations
        for (int t = 0; t < tmax; t++) {
            // ---- per-wave reduce (6 DPP mins, result in lane63) ----
            unsigned wmin = wave_min_to_lane63(rk);
            if (lane == 63) xm[par][wid] = wmin;
            __syncthreads();

            // ---- cross-wave combine: broadcast b128 read of 4 minima ----
            u32x4 xv = *reinterpret_cast<const u32x4*>(&xm[par][0]);
            unsigned vm = umin3(xv.x, xv.y, xv.z);
            vm = vm < xv.w ? vm : xv.w;
            unsigned wk = (unsigned)__builtin_amdgcn_readfirstlane((int)vm) + 1024u;
            par ^= 1;

            unsigned j = wk & 1023u;
            int wslot = (int)(j >> 6);
            int wlane = (int)(j & 63u);

            // ---- pj (shifted coords) from replicated regs: SEL16+readlane --
            bool b0 = (wslot & 1) != 0, b1 = (wslot & 2) != 0;
            bool b2 = (wslot & 4) != 0, b3 = (wslot & 8) != 0;
            unsigned selPay;
            SEL16(p, selPay);
            unsigned pjs = (unsigned)__builtin_amdgcn_readlane((int)selPay, wlane);

            // ---- edge record: cndmask accumulate into lane t ----
            acc = (lane == t) ? wk : acc;

            // ---- decrease-key on own 4 slots; extracted slot self-kills ----
            { unsigned nk = mk_key(oq0, pjs, oi0);
              ok0 = (unsigned)min((int)ok0, (int)nk); }
            { unsigned nk = mk_key(oq1, pjs, oi1);
              ok1 = (unsigned)min((int)ok1, (int)nk); }
            { unsigned nk = mk_key(oq2, pjs, oi2);
              ok2 = (unsigned)min((int)ok2, (int)nk); }
            { unsigned nk = mk_key(oq3, pjs, oi3);
              ok3 = (unsigned)min((int)ok3, (int)nk); }
            unsigned r3 = umin3(ok0, ok1, ok2);
            rk = r3 < ok3 ? r3 : ok3;       // next iteration's per-lane min
        }
        // wave 0 does the full-wave coalesced batch store; chk=15 lane63
        // writes eout[1023] (stale value) which is never read downstream.
        // These bytes are image m's own maskbit chunks 0-1, already consumed
        // by THIS block's select phase -> no cross-block hazard.
        if (wid == 0) eout[(chk << 6) + lane] = acc;
    }
}

// ---------------------------------------------------------------------------
// Kernel 3 (phase 2): recover src per edge + per-edge (Dp-Dm)^2.
// Same logic; edges at wsW + m*IMGW, contrib at wsW + m*IMGW + 2048 (f32).
// ---------------------------------------------------------------------------
__global__ void recover_kernel(const unsigned* __restrict__ ptsG,
                               unsigned* __restrict__ wsW) {
    __shared__ unsigned sS[KPTS];
    __shared__ unsigned sO[KPTS];
    __shared__ unsigned short sT[KPTS];   // extraction time + 1 (0 = root)
    int g = blockIdx.x, m = blockIdx.y;
    int tid = threadIdx.x;
    int partner = m ^ 1;
    const unsigned* edges = wsW + m * IMGW;
    float* contrib = (float*)(wsW + m * IMGW + 2048);

    for (int i = tid; i < KPTS; i += 256) {
        sS[i] = ptsG[m * KPTS + i];
        sO[i] = ptsG[partner * KPTS + i];
    }
    for (int e = tid; e < KPTS - 1; e += 256) {
        unsigned wkk = edges[e];
        sT[wkk & 1023u] = (unsigned short)(e + 1);
    }
    if (tid == 0) sT[0] = 0;
    __syncthreads();

    int lane = tid & 63, w = tid >> 6;
    for (int k = 0; k < 16; k++) {
        int e = g * 64 + w * 16 + k;
        if (e >= KPTS - 1) break;            // only e=1023 (g=15,w=3,k=15)
        unsigned wk = edges[e];
        unsigned j = wk & 1023u;
        unsigned d2p = wk >> 10;
        unsigned pj = sS[j];
        unsigned te1 = (unsigned)(e + 1);

        unsigned best = 0xFFFFFFFFu;
#pragma unroll
        for (int i = 0; i < 16; i++) {
            int v = i * 64 + lane;
            unsigned pv = sS[v];
            int d2 = dist2_packed(pv, pj);
            unsigned tv1 = (unsigned)sT[v];
            bool qual = ((unsigned)d2 == d2p) && (tv1 < te1);
            unsigned cand = qual ? ((tv1 << 10) | (unsigned)v) : 0xFFFFFFFFu;
            best = cand < best ? cand : best;
        }
#pragma unroll
        for (int dd = 32; dd; dd >>= 1) {
            unsigned o = (unsigned)__shfl_xor((int)best, dd, 64);
            best = o < best ? o : best;
        }
        unsigned vsrc = best & 1023u;
        if (lane == 0) {
            unsigned oj = sO[j], os = sO[vsrc];
            float Dp = __fsqrt_rn((float)d2p);
            float Dm = __fsqrt_rn((float)dist2_packed(oj, os));
            float diff = Dp - Dm;
            contrib[e] = diff * diff;
        }
    }
}

// ---------------------------------------------------------------------------
// Kernel 4: per-image f64 sum (extraction order e=0..1022, deterministic —
// bit-identical to the previous final_kernel) -> loss
// ---------------------------------------------------------------------------
__global__ void final_kernel(const unsigned* __restrict__ wsW,
                             float* __restrict__ out) {
    __shared__ double part[NIMG];
    int t = threadIdx.x;
    if (t < NIMG) {
        const float* contrib = (const float*)(wsW + t * IMGW + 2048);
        double s = 0.0;
        for (int e = 0; e < KPTS - 1; e++)
            s += (double)contrib[e];
        part[t] = sqrt(s);
    }
    __syncthreads();
    if (t == 0) {
        double tot = 0.0;
        for (int i = 0; i < NIMG; i++) tot += part[i];
        out[0] = (float)(0.1 * tot / 8.0);
    }
}

// ---------------------------------------------------------------------------
// ws layout (u32 words; per-image region = IMGW=8192 words = image m's own
// 32KB maskbit area):
//   [0,512K)bytes    maskbits (lbp->selmst); inside image m's region:
//     words [m*IMGW, m*IMGW+1024)        edges   (selmst->recover; overwrites
//                                        m's own chunks 0-1, post-consumption)
//     words [m*IMGW+2048, m*IMGW+3071)   contrib (recover->final)
//   [512K,576K)bytes ptsG (selmst->recover)
// ---------------------------------------------------------------------------
extern "C" void kernel_launch(void* const* d_in, const int* in_sizes, int n_in,
                              void* d_out, int out_size, void* d_ws, size_t ws_size,
                              hipStream_t stream) {
    const float* mo = (const float*)d_in[1];   // model_output
    const float* lb = (const float*)d_in[2];   // labels

    unsigned long long* maskbits = (unsigned long long*)d_ws;
    unsigned* wsW = (unsigned*)d_ws;
    unsigned* ptsG = (unsigned*)((char*)d_ws + (size_t)NIMG * NWORDS * 8);
    float* out = (float*)d_out;

    lbp_kernel<<<dim3(NPIX / 256, NIMG), 256, 0, stream>>>(mo, lb, maskbits);
    selmst_kernel<<<NIMG, 256, 0, stream>>>(maskbits, ptsG, wsW);
    recover_kernel<<<dim3(16, NIMG), 256, 0, stream>>>(ptsG, wsW);
    final_kernel<<<1, 64, 0, stream>>>(wsW, out);
}

// Round 11
// 391.376 us; speedup vs baseline: 1.7839x; 1.0384x over previous
//
#include <hip/hip_runtime.h>

#define HH 512
#define WW 512
#define NPIX (HH * WW)          // 262144
#define NIMG 16
#define KPTS 1024
#define NWORDS (NPIX / 64)      // 4096 u64 mask words per image
#define IMGW 8192               // u32 words per image region in ws (32 KB)

// ---------------------------------------------------------------------------
// Kernel 1: binarize + uniform LBP (P=8,R=1) — PURE BOOLEAN form. (unchanged)
// ---------------------------------------------------------------------------
__global__ void lbp_kernel(const float* __restrict__ mo,
                           const float* __restrict__ lb,
                           unsigned long long* __restrict__ maskbits) {
    int m = blockIdx.y;                    // image 0..15: even=pred, odd=mask
    int pix = blockIdx.x * blockDim.x + threadIdx.x;   // 0..262143
    int r = pix >> 9, c = pix & 511;
    int sample = m >> 1;
    const float* img = (m & 1) ? (lb + sample * NPIX) : (mo + sample * NPIX);
    float thr = (m & 1) ? 0.5f : 0.0f;     // sigmoid(x)>0.5 <=> x>0

    int rm = r - (r > 0), rp = r + (r < HH - 1);
    int cm = c - (c > 0), cp = c + (c < WW - 1);
    const float* rowm = img + rm * WW;
    const float* row0 = img + r  * WW;
    const float* rowp = img + rp * WW;

    bool bmm = rowm[cm] > thr, bm0 = rowm[c] > thr, bmp = rowm[cp] > thr;
    bool b0m = row0[cm] > thr, b00 = row0[c] > thr, b0p = row0[cp] > thr;
    bool bpm = rowp[cm] > thr, bp0 = rowp[c] > thr, bpp = rowp[cp] > thr;

    bool r0e = (r == 0), c0e = (c == 0);
    bool t2m = r0e ? bpm : b0m;    // B(row2, cm)
    bool t2c = r0e ? bp0 : b00;    // B(row2, c)
    bool t2p = r0e ? bpp : b0p;    // B(row2, cp)
    bool mc2 = c0e ? bmp : bm0;    // B(rm,  col2)
    bool tc2 = c0e ? t2p : t2c;    // B(row2,col2)
    bool zc2 = c0e ? b0p : b00;    // B(r,   col2)
    bool pc2 = c0e ? bpp : bp0;    // B(rp,  col2)

    unsigned bb =
        (b0p                     ?   1u : 0u)
      | ((bm0 & bmp & t2c & t2p) ?   2u : 0u)
      | (bm0                     ?   4u : 0u)
      | ((bmm & mc2 & t2m & tc2) ?   8u : 0u)
      | (b0m                     ?  16u : 0u)
      | ((b0m & zc2 & bpm & pc2) ?  32u : 0u)
      | (bp0                     ?  64u : 0u)
      | ((b0p & bp0 & bpp)       ? 128u : 0u);

    unsigned rol = ((bb << 1) | (bb >> 7)) & 0xFFu;
    int changes = __popc(bb ^ rol);
    int s = __popc(bb);
    bool maskbit = b00 && (changes <= 2) && (s < 5);   // lbp < THR(=5)

    unsigned long long w = __ballot(maskbit);
    if ((threadIdx.x & 63) == 0)
        maskbits[m * NWORDS + (pix >> 6)] = w;
}

// ---------------------------------------------------------------------------
// Kernel 2 (FUSED select + mst): grid 16 x 256. (unchanged from R10)
//   Phase A (select): stable row-major compaction to K=1024 packed points,
//     written BOTH to global ptsG (for recover) and an LDS copy sP.
//   Phase B (mst): the proven R1 structure, bit-exact (657 cy/iter best of
//     9 measured variants), points from sP.
// WS RACE DISCIPLINE: edges for image m live INSIDE image m's own 32KB
// maskbit region (chunks 0-1, consumed by the same block's select phase
// before the mst phase writes them). contrib at words [2048,3071) of the
// same region, written only by recover.
// ---------------------------------------------------------------------------
typedef short v2s __attribute__((ext_vector_type(2)));
typedef unsigned u32x4 __attribute__((ext_vector_type(4)));

__device__ __forceinline__ int dist2_packed(unsigned a, unsigned b) {
#if __has_builtin(__builtin_amdgcn_sdot2)
    v2s d = __builtin_bit_cast(v2s, a) - __builtin_bit_cast(v2s, b);
    return __builtin_amdgcn_sdot2(d, d, 0, false);
#else
    int dr = (int)(a >> 16) - (int)(b >> 16);
    int dc = (int)(a & 0xFFFFu) - (int)(b & 0xFFFFu);
    return __mul24(dr, dr) + __mul24(dc, dc);
#endif
}

template <int CTRL>
__device__ __forceinline__ unsigned umin_dpp(unsigned x) {
    unsigned o = (unsigned)__builtin_amdgcn_update_dpp((int)x, (int)x, CTRL,
                                                       0xf, 0xf, false);
    return o < x ? o : x;
}

// full-wave unsigned-min; result valid in lane 63 only.
__device__ __forceinline__ unsigned wave_min_to_lane63(unsigned x) {
    x = umin_dpp<0x111>(x);   // row_shr:1
    x = umin_dpp<0x112>(x);   // row_shr:2
    x = umin_dpp<0x114>(x);   // row_shr:4
    x = umin_dpp<0x118>(x);   // row_shr:8  -> lane15 of each 16-row
    x = umin_dpp<0x142>(x);   // row_bcast:15
    x = umin_dpp<0x143>(x);   // row_bcast:31 -> lane63 = wave min
    return x;
}

__device__ __forceinline__ unsigned umin3(unsigned a, unsigned b, unsigned c) {
    unsigned t = a < b ? a : b;          // fuses to v_min3_u32
    return t < c ? t : c;
}

// biased key: coords pre-shifted <<5 so sdot2 gives d2<<10; acc = idx-1024
__device__ __forceinline__ unsigned mk_key(unsigned ps, unsigned qs, int izb) {
#if __has_builtin(__builtin_amdgcn_sdot2)
    v2s d = __builtin_bit_cast(v2s, ps) - __builtin_bit_cast(v2s, qs);
    return (unsigned)__builtin_amdgcn_sdot2(d, d, izb, false);
#else
    int dr = (int)(short)(ps >> 16) - (int)(short)(qs >> 16);
    int dc = (int)(short)(ps & 0xFFFFu) - (int)(short)(qs & 0xFFFFu);
    return (unsigned)(dr * dr + dc * dc + izb);
#endif
}

// uniform select of points[wslot][wlane] from 16 replicated regs
#define SEL16(P, res)                                                     \
    { unsigned _a0 = b0 ? P##1  : P##0;                                   \
      unsigned _a1 = b0 ? P##3  : P##2;                                   \
      unsigned _a2 = b0 ? P##5  : P##4;                                   \
      unsigned _a3 = b0 ? P##7  : P##6;                                   \
      unsigned _a4 = b0 ? P##9  : P##8;                                   \
      unsigned _a5 = b0 ? P##11 : P##10;                                  \
      unsigned _a6 = b0 ? P##13 : P##12;                                  \
      unsigned _a7 = b0 ? P##15 : P##14;                                  \
      unsigned _c0 = b1 ? _a1 : _a0;                                      \
      unsigned _c1 = b1 ? _a3 : _a2;                                      \
      unsigned _c2 = b1 ? _a5 : _a4;                                      \
      unsigned _c3 = b1 ? _a7 : _a6;                                      \
      unsigned _e0 = b2 ? _c1 : _c0;                                      \
      unsigned _e1 = b2 ? _c3 : _c2;                                      \
      res = b3 ? _e1 : _e0; }

#define LOADP(P, B)                                                       \
    unsigned P##0  = B[( 0 << 6) | lane] << 5;                            \
    unsigned P##1  = B[( 1 << 6) | lane] << 5;                            \
    unsigned P##2  = B[( 2 << 6) | lane] << 5;                            \
    unsigned P##3  = B[( 3 << 6) | lane] << 5;                            \
    unsigned P##4  = B[( 4 << 6) | lane] << 5;                            \
    unsigned P##5  = B[( 5 << 6) | lane] << 5;                            \
    unsigned P##6  = B[( 6 << 6) | lane] << 5;                            \
    unsigned P##7  = B[( 7 << 6) | lane] << 5;                            \
    unsigned P##8  = B[( 8 << 6) | lane] << 5;                            \
    unsigned P##9  = B[( 9 << 6) | lane] << 5;                            \
    unsigned P##10 = B[(10 << 6) | lane] << 5;                            \
    unsigned P##11 = B[(11 << 6) | lane] << 5;                            \
    unsigned P##12 = B[(12 << 6) | lane] << 5;                            \
    unsigned P##13 = B[(13 << 6) | lane] << 5;                            \
    unsigned P##14 = B[(14 << 6) | lane] << 5;                            \
    unsigned P##15 = B[(15 << 6) | lane] << 5;

__global__ __launch_bounds__(256, 1) void selmst_kernel(
        const unsigned long long* __restrict__ maskbits,
        unsigned* __restrict__ ptsG,
        unsigned* __restrict__ wsW) {
    __shared__ unsigned sP[KPTS];                 // LDS copy of packed points
    __shared__ unsigned swv[4];
    __shared__ __align__(16) unsigned xm[2][4];   // parity double-buffer
    int tid = threadIdx.x;
    int lane = tid & 63, wid = tid >> 6;
    int m = blockIdx.x;

    // ================= Phase A: select (identical logic) =================
    unsigned* ptsOut = ptsG + m * KPTS;
    for (int i = tid; i < KPTS; i += 256) { ptsOut[i] = 0u; sP[i] = 0u; }
    __syncthreads();

    unsigned running = 0;
    for (int ch = 0; ch < 16; ch++) {
        int w = ch * 256 + tid;
        unsigned long long word = maskbits[m * NWORDS + w];
        unsigned cnt = (unsigned)__popcll(word);

        unsigned x = cnt;                    // intra-wave inclusive scan
#pragma unroll
        for (int d = 1; d < 64; d <<= 1) {
            unsigned y = (unsigned)__shfl_up((int)x, d, 64);
            x += (lane >= d) ? y : 0u;
        }
        if (lane == 63) swv[wid] = x;
        __syncthreads();
        unsigned woff = 0, total = 0;
#pragma unroll
        for (int ww = 0; ww < 4; ww++) {
            unsigned tt = swv[ww];
            total += tt;
            woff += (ww < wid) ? tt : 0u;
        }
        unsigned rank = running + woff + x - cnt;   // exclusive prefix
        while (word) {
            int bpos = __builtin_ctzll(word);
            word &= word - 1;
            if (rank < (unsigned)KPTS) {
                unsigned pv = (unsigned)(w * 64 + bpos);
                unsigned packed = ((pv >> 9) << 16) | (pv & 511u);
                ptsOut[rank] = packed;
                sP[rank] = packed;
            }
            rank++;
        }
        running += total;
        if (running >= (unsigned)KPTS) break;   // uniform -> safe
        __syncthreads();   // protect swv before next chunk
    }
    __syncthreads();       // sP complete before mst phase reads it

    // ============ Phase B: mst (R1 structure, points from LDS) ===========
    unsigned pt0s = sP[0] << 5;      // self point 0, shifted (uniform)
    LOADP(p, sP)                     // replicated point set from LDS

    // this wave's 4 owned key slots: global slot = wid*4 + sl
    int oi0 = (((wid * 4 + 0) << 6) | lane) - 1024;
    int oi1 = (((wid * 4 + 1) << 6) | lane) - 1024;
    int oi2 = (((wid * 4 + 2) << 6) | lane) - 1024;
    int oi3 = (((wid * 4 + 3) << 6) | lane) - 1024;
    unsigned oq0 = sP[((wid * 4 + 0) << 6) | lane] << 5;
    unsigned oq1 = sP[((wid * 4 + 1) << 6) | lane] << 5;
    unsigned oq2 = sP[((wid * 4 + 2) << 6) | lane] << 5;
    unsigned oq3 = sP[((wid * 4 + 3) << 6) | lane] << 5;
    unsigned ok0 = mk_key(oq0, pt0s, oi0);   // node0 self-kills
    unsigned ok1 = mk_key(oq1, pt0s, oi1);
    unsigned ok2 = mk_key(oq2, pt0s, oi2);
    unsigned ok3 = mk_key(oq3, pt0s, oi3);

    unsigned* eout = wsW + m * IMGW;     // image m's OWN region (see header)
    unsigned r3i = umin3(ok0, ok1, ok2);
    unsigned rk = r3i < ok3 ? r3i : ok3;    // per-lane min over own 4 slots

    unsigned acc = 0;                // per-lane edge accumulator (batch of 64)
    int par = 0;

    for (int chk = 0; chk < 16; chk++) {
        int tmax = (chk < 15) ? 64 : 63;     // 15*64 + 63 = 1023 iterations
        for (int t = 0; t < tmax; t++) {
            // ---- per-wave reduce (6 DPP mins, result in lane63) ----
            unsigned wmin = wave_min_to_lane63(rk);
            if (lane == 63) xm[par][wid] = wmin;
            __syncthreads();

            // ---- cross-wave combine: broadcast b128 read of 4 minima ----
            u32x4 xv = *reinterpret_cast<const u32x4*>(&xm[par][0]);
            unsigned vm = umin3(xv.x, xv.y, xv.z);
            vm = vm < xv.w ? vm : xv.w;
            unsigned wk = (unsigned)__builtin_amdgcn_readfirstlane((int)vm) + 1024u;
            par ^= 1;

            unsigned j = wk & 1023u;
            int wslot = (int)(j >> 6);
            int wlane = (int)(j & 63u);

            // ---- pj (shifted coords) from replicated regs: SEL16+readlane --
            bool b0 = (wslot & 1) != 0, b1 = (wslot & 2) != 0;
            bool b2 = (wslot & 4) != 0, b3 = (wslot & 8) != 0;
            unsigned selPay;
            SEL16(p, selPay);
            unsigned pjs = (unsigned)__builtin_amdgcn_readlane((int)selPay, wlane);

            // ---- edge record: cndmask accumulate into lane t ----
            acc = (lane == t) ? wk : acc;

            // ---- decrease-key on own 4 slots; extracted slot self-kills ----
            { unsigned nk = mk_key(oq0, pjs, oi0);
              ok0 = (unsigned)min((int)ok0, (int)nk); }
            { unsigned nk = mk_key(oq1, pjs, oi1);
              ok1 = (unsigned)min((int)ok1, (int)nk); }
            { unsigned nk = mk_key(oq2, pjs, oi2);
              ok2 = (unsigned)min((int)ok2, (int)nk); }
            { unsigned nk = mk_key(oq3, pjs, oi3);
              ok3 = (unsigned)min((int)ok3, (int)nk); }
            unsigned r3 = umin3(ok0, ok1, ok2);
            rk = r3 < ok3 ? r3 : ok3;       // next iteration's per-lane min
        }
        // wave 0 does the full-wave coalesced batch store; chk=15 lane63
        // writes eout[1023] (stale value) which is never read downstream.
        // These bytes are image m's own maskbit chunks 0-1, already consumed
        // by THIS block's select phase -> no cross-block hazard.
        if (wid == 0) eout[(chk << 6) + lane] = acc;
    }
}

// ---------------------------------------------------------------------------
// Kernel 3 (phase 2): recover src per edge + per-edge (Dp-Dm)^2. (unchanged)
// edges at wsW + m*IMGW, contrib at wsW + m*IMGW + 2048 (f32).
// ---------------------------------------------------------------------------
__global__ void recover_kernel(const unsigned* __restrict__ ptsG,
                               unsigned* __restrict__ wsW) {
    __shared__ unsigned sS[KPTS];
    __shared__ unsigned sO[KPTS];
    __shared__ unsigned short sT[KPTS];   // extraction time + 1 (0 = root)
    int g = blockIdx.x, m = blockIdx.y;
    int tid = threadIdx.x;
    int partner = m ^ 1;
    const unsigned* edges = wsW + m * IMGW;
    float* contrib = (float*)(wsW + m * IMGW + 2048);

    for (int i = tid; i < KPTS; i += 256) {
        sS[i] = ptsG[m * KPTS + i];
        sO[i] = ptsG[partner * KPTS + i];
    }
    for (int e = tid; e < KPTS - 1; e += 256) {
        unsigned wkk = edges[e];
        sT[wkk & 1023u] = (unsigned short)(e + 1);
    }
    if (tid == 0) sT[0] = 0;
    __syncthreads();

    int lane = tid & 63, w = tid >> 6;
    for (int k = 0; k < 16; k++) {
        int e = g * 64 + w * 16 + k;
        if (e >= KPTS - 1) break;            // only e=1023 (g=15,w=3,k=15)
        unsigned wk = edges[e];
        unsigned j = wk & 1023u;
        unsigned d2p = wk >> 10;
        unsigned pj = sS[j];
        unsigned te1 = (unsigned)(e + 1);

        unsigned best = 0xFFFFFFFFu;
#pragma unroll
        for (int i = 0; i < 16; i++) {
            int v = i * 64 + lane;
            unsigned pv = sS[v];
            int d2 = dist2_packed(pv, pj);
            unsigned tv1 = (unsigned)sT[v];
            bool qual = ((unsigned)d2 == d2p) && (tv1 < te1);
            unsigned cand = qual ? ((tv1 << 10) | (unsigned)v) : 0xFFFFFFFFu;
            best = cand < best ? cand : best;
        }
#pragma unroll
        for (int dd = 32; dd; dd >>= 1) {
            unsigned o = (unsigned)__shfl_xor((int)best, dd, 64);
            best = o < best ? o : best;
        }
        unsigned vsrc = best & 1023u;
        if (lane == 0) {
            unsigned oj = sO[j], os = sO[vsrc];
            float Dp = __fsqrt_rn((float)d2p);
            float Dm = __fsqrt_rn((float)dist2_packed(oj, os));
            float diff = Dp - Dm;
            contrib[e] = diff * diff;
        }
    }
}

// ---------------------------------------------------------------------------
// Kernel 4: final reduction, PARALLELIZED. Previous version: one wave, 16
// active lanes, each looping 1023 global loads at 32KB lane stride (every
// wave-load = 16 cache lines) + a serial dependent f64 add chain — the
// prime suspect for the unexplained residue. Now: 1024 threads = 16 waves;
// wave w owns image w; lane l sums e = i*64+l (COALESCED within the image's
// contrib array, 16 loads/lane, 16 waves hide latency), then f64 shfl_xor
// butterfly. Within-image f64 regrouping perturbs the sum by ~1e-13
// relative — invisible after sqrt + f32 cast. Cross-image sum stays in
// image order (unchanged).
// ---------------------------------------------------------------------------
__global__ __launch_bounds__(1024, 1) void final_kernel(
        const unsigned* __restrict__ wsW,
        float* __restrict__ out) {
    __shared__ double part[NIMG];
    int tid = threadIdx.x;           // 0..1023
    int lane = tid & 63, w = tid >> 6;   // w = image 0..15
    const float* contrib = (const float*)(wsW + w * IMGW + 2048);

    double s = 0.0;
#pragma unroll
    for (int i = 0; i < 16; i++) {
        int e = i * 64 + lane;
        s += (e < KPTS - 1) ? (double)contrib[e] : 0.0;
    }
#pragma unroll
    for (int d = 32; d; d >>= 1)
        s += __shfl_xor(s, d, 64);
    if (lane == 0) part[w] = sqrt(s);
    __syncthreads();
    if (tid == 0) {
        double tot = 0.0;
        for (int i = 0; i < NIMG; i++) tot += part[i];
        out[0] = (float)(0.1 * tot / 8.0);
    }
}

// ---------------------------------------------------------------------------
// ws layout (u32 words; per-image region = IMGW=8192 words = image m's own
// 32KB maskbit area):
//   [0,512K)bytes    maskbits (lbp->selmst); inside image m's region:
//     words [m*IMGW, m*IMGW+1024)        edges   (selmst->recover; overwrites
//                                        m's own chunks 0-1, post-consumption)
//     words [m*IMGW+2048, m*IMGW+3071)   contrib (recover->final)
//   [512K,576K)bytes ptsG (selmst->recover)
// ---------------------------------------------------------------------------
extern "C" void kernel_launch(void* const* d_in, const int* in_sizes, int n_in,
                              void* d_out, int out_size, void* d_ws, size_t ws_size,
                              hipStream_t stream) {
    const float* mo = (const float*)d_in[1];   // model_output
    const float* lb = (const float*)d_in[2];   // labels

    unsigned long long* maskbits = (unsigned long long*)d_ws;
    unsigned* wsW = (unsigned*)d_ws;
    unsigned* ptsG = (unsigned*)((char*)d_ws + (size_t)NIMG * NWORDS * 8);
    float* out = (float*)d_out;

    lbp_kernel<<<dim3(NPIX / 256, NIMG), 256, 0, stream>>>(mo, lb, maskbits);
    selmst_kernel<<<NIMG, 256, 0, stream>>>(maskbits, ptsG, wsW);
    recover_kernel<<<dim3(16, NIMG), 256, 0, stream>>>(ptsG, wsW);
    final_kernel<<<1, 1024, 0, stream>>>(wsW, out);
}